// Round 11
// baseline (346.943 us; speedup 1.0000x reference)
//
#include <hip/hip_runtime.h>
#include <math.h>

// Problem constants (B=2, T=2048, D=512, H=8, hd=64, K=16, DEPTH=3)
#define TSEQ   2048
#define DM     512
#define NH     8
#define HD     64
#define KATT   16
#define NDEPTH 3
#define MROWS  4096   // B*T

typedef __attribute__((ext_vector_type(8))) short bf16x8;
typedef __attribute__((ext_vector_type(8))) unsigned short u16x8;
typedef __attribute__((ext_vector_type(4))) float f32x4;

// f32 -> bf16 (round-to-nearest-even), bit-level
static __device__ __forceinline__ unsigned short f2b(float f) {
    unsigned int u = __float_as_uint(f);
    unsigned int r = (u + 0x7fffu + ((u >> 16) & 1u)) >> 16;
    return (unsigned short)r;
}
// bf16 bits -> f32
static __device__ __forceinline__ float b2f(unsigned short s) {
    return __uint_as_float((unsigned int)s << 16);
}

// global -> LDS direct DMA, 16 B per lane; HW writes lane i at lds + i*16.
static __device__ __forceinline__ void load_lds16(const void* g, void* l) {
    __builtin_amdgcn_global_load_lds(
        (const __attribute__((address_space(1))) unsigned int*)g,
        (__attribute__((address_space(3))) unsigned int*)l, 16, 0, 0);
}

// branchless erf, A&S 7.1.26, |err| <= 1.5e-7
static __device__ __forceinline__ float fast_erf(float x) {
    const float a  = fabsf(x);
    const float t  = 1.0f / (1.0f + 0.3275911f * a);
    const float p  = t * (0.254829592f + t * (-0.284496736f +
                     t * (1.421413741f + t * (-1.453152027f + t * 1.061405429f))));
    const float e  = __expf(-a * a);
    const float r  = 1.0f - p * e;
    return __builtin_copysignf(r, x);
}

// ---------------------------------------------------------------------------
// Prep: ALL weight transposes (f32 [K x N] x3 depth -> bf16 [N x K]) PLUS the
// depth-0 LN1 (x f32 -> hbuf bf16), merged into one launch.
// ---------------------------------------------------------------------------
__global__ __launch_bounds__(256) void prep_kernel(
    const float* __restrict__ qkv_w, const float* __restrict__ proj_w,
    const float* __restrict__ w1,    const float* __restrict__ w2,
    unsigned short* __restrict__ qkvT, unsigned short* __restrict__ projT,
    unsigned short* __restrict__ w1T,  unsigned short* __restrict__ w2T,
    const float* __restrict__ x, const float* __restrict__ sc,
    const float* __restrict__ bi, unsigned short* __restrict__ h)
{
    __shared__ float tile[32][33];
    int id = blockIdx.x;
    const int tid = threadIdx.x;

    if (id < 9216) {
        const float* W; unsigned short* Wt; int Kd, Nd;
        if (id < 2304)      { W = qkv_w;  Wt = qkvT;  Kd = 512;  Nd = 1536; }
        else if (id < 3072) { W = proj_w; Wt = projT; Kd = 512;  Nd = 512;  id -= 2304; }
        else if (id < 6144) { W = w1;     Wt = w1T;   Kd = 512;  Nd = 2048; id -= 3072; }
        else                { W = w2;     Wt = w2T;   Kd = 2048; Nd = 512;  id -= 6144; }
        const int nt = Nd >> 5, per = nt * (Kd >> 5);
        const int d = id / per, rem = id % per;
        const int k0 = (rem / nt) * 32, n0 = (rem % nt) * 32;

        const size_t off = (size_t)d * Kd * Nd;
        const float* Wd = W + off;
        unsigned short* Wtd = Wt + off;
        const int tx = tid & 31, ty = tid >> 5;
#pragma unroll
        for (int r = 0; r < 32; r += 8)
            tile[ty + r][tx] = Wd[(size_t)(k0 + ty + r) * Nd + (n0 + tx)];
        __syncthreads();
#pragma unroll
        for (int r = 0; r < 32; r += 8)
            Wtd[(size_t)(n0 + ty + r) * Kd + (k0 + tx)] = f2b(tile[tx][ty + r]);
        return;
    }

    // ---- LN part ----
    const int wid  = (id - 9216) * 4 + (tid >> 6);
    const int lane = tid & 63;
    const float* xr = x + (size_t)wid * DM;
    const float4 v0 = *(const float4*)&xr[lane * 4];
    const float4 v1 = *(const float4*)&xr[256 + lane * 4];
    float s = v0.x + v0.y + v0.z + v0.w + v1.x + v1.y + v1.z + v1.w;
    float q = v0.x*v0.x + v0.y*v0.y + v0.z*v0.z + v0.w*v0.w
            + v1.x*v1.x + v1.y*v1.y + v1.z*v1.z + v1.w*v1.w;
#pragma unroll
    for (int off = 32; off; off >>= 1) {
        s += __shfl_xor(s, off, 64);
        q += __shfl_xor(q, off, 64);
    }
    const float mean = s * (1.0f / DM);
    const float var  = q * (1.0f / DM) - mean * mean;
    const float rs   = rsqrtf(var + 1e-5f);
    unsigned short* hr = h + (size_t)wid * DM;
    const int c0 = lane * 4, c1 = 256 + lane * 4;
    ushort4 o0, o1;
    o0.x = f2b((v0.x - mean) * rs * sc[c0+0] + bi[c0+0]);
    o0.y = f2b((v0.y - mean) * rs * sc[c0+1] + bi[c0+1]);
    o0.z = f2b((v0.z - mean) * rs * sc[c0+2] + bi[c0+2]);
    o0.w = f2b((v0.w - mean) * rs * sc[c0+3] + bi[c0+3]);
    o1.x = f2b((v1.x - mean) * rs * sc[c1+0] + bi[c1+0]);
    o1.y = f2b((v1.y - mean) * rs * sc[c1+1] + bi[c1+1]);
    o1.z = f2b((v1.z - mean) * rs * sc[c1+2] + bi[c1+2]);
    o1.w = f2b((v1.w - mean) * rs * sc[c1+3] + bi[c1+3]);
    *(ushort4*)&hr[c0] = o0;
    *(ushort4*)&hr[c1] = o1;
}

// ---------------------------------------------------------------------------
// Dilated attention, 32-query tiles (R21), K/V/Q staged in LDS, XCD-chunked
// swizzle, b32 dim-pair phase 2.
// ---------------------------------------------------------------------------
__global__ __launch_bounds__(256) void attn_kernel(
    const unsigned short* __restrict__ qh, const unsigned short* __restrict__ kh,
    const unsigned short* __restrict__ vh, unsigned short* __restrict__ o, int dil)
{
    const int nwg = gridDim.x;                         // 1024, %8 == 0
    const int wg  = (blockIdx.x & 7) * (nwg >> 3) + (blockIdx.x >> 3);
    const int tile = wg & (TSEQ / 32 - 1);   // 64 query tiles of 32
    const int bh   = wg >> 6;
    const int b    = bh >> 3, hh = bh & 7;
    const int t0   = tile * 32;
    const int tid  = threadIdx.x;
    const int wave = tid >> 6, lane = tid & 63;
    const int s    = lane & 15;               // key slot 0..15
    const size_t slab = ((size_t)hh * MROWS + (size_t)b * TSEQ) * HD;

    const int R    = 15 * dil + 32;           // staged rows: 47 / 62 / 92
    const int base = t0 - 15 * dil;

    __shared__ unsigned short ks[92 * 64];
    __shared__ unsigned short vs[92 * 64];
    __shared__ unsigned short qs[32 * 64];
    __shared__ float p_lds[32][17];

    // ---- stage K/V rows [base, base+R) (row-0-clamped) + Q tile ----
    for (int c = tid; c < R * 8; c += 256) {
        const int r = c >> 3, cs = c & 7;
        const int sr = max(base + r, 0);      // clamped rows get weight 0 later
        const int ps = ((cs + r + (r >> 2)) & 7) * 8;
        const size_t g = slab + (size_t)sr * HD + cs * 8;
        *(u16x8*)&ks[r * 64 + ps] = *(const u16x8*)(kh + g);
        *(u16x8*)&vs[r * 64 + ps] = *(const u16x8*)(vh + g);
    }
    {   // Q: 32 rows x 8 chunks = 256 = one chunk per thread
        const int r = tid >> 3, cs = tid & 7;
        *(u16x8*)&qs[r * 64 + cs * 8] =
            *(const u16x8*)(qh + slab + (size_t)(t0 + r) * HD + cs * 8);
    }
    __syncthreads();

    // ---- phase 1: scores + softmax; 2 (q, slot) pairs per lane ----
#pragma unroll
    for (int qi = 0; qi < 2; qi++) {
        const int tq = wave * 8 + qi * 4 + (lane >> 4);   // query 0..31
        const int t  = t0 + tq;
        const bool valid = (t - s * dil) >= 0;
        const int  kidx  = tq + 15 * dil - s * dil;       // staged index
        float dot = 0.0f;
#pragma unroll
        for (int j = 0; j < 8; j++) {
            const u16x8 kk = *(const u16x8*)&ks[kidx * 64 + (((j + kidx + (kidx >> 2)) & 7) * 8)];
            const u16x8 qq = *(const u16x8*)&qs[tq * 64 + j * 8];
#pragma unroll
            for (int e = 0; e < 8; e++) dot += b2f(qq[e]) * b2f(kk[e]);
        }
        const float sc = valid ? dot * 0.125f : -1e30f;
        float m = sc;
#pragma unroll
        for (int off = 1; off < 16; off <<= 1) m = fmaxf(m, __shfl_xor(m, off, 64));
        const float p = expf(sc - m);
        float l = p;
#pragma unroll
        for (int off = 1; off < 16; off <<= 1) l += __shfl_xor(l, off, 64);
        p_lds[tq][s] = p / l;
    }
    __syncthreads();

    // ---- phase 2: o = sum_s p * v ; 32 lanes x 2 dims, 4 q-iterations ----
    const int dp  = lane & 31;                // dim-pair index: dims 2dp, 2dp+1
    const int qh2 = lane >> 5;                // 0/1
#pragma unroll
    for (int qi = 0; qi < 4; qi++) {
        const int qq = qi * 8 + wave * 2 + qh2;           // query 0..31
        float a0 = 0.0f, a1 = 0.0f;
#pragma unroll
        for (int ss = 0; ss < KATT; ss++) {
            const int idx = qq + 15 * dil - ss * dil;     // staged V row
            const float pw = p_lds[qq][ss];               // exactly 0 for masked slots
            const int ch = ((dp >> 2) + idx + (idx >> 2)) & 7;
            const unsigned int vv =
                *(const unsigned int*)&vs[idx * 64 + ch * 8 + (dp & 3) * 2];
            a0 += pw * b2f((unsigned short)(vv & 0xffffu));
            a1 += pw * b2f((unsigned short)(vv >> 16));
        }
        unsigned short* orow = o + (size_t)(b * TSEQ + (t0 + qq)) * DM + (size_t)hh * HD;
        const unsigned int packed = (unsigned int)f2b(a0) | ((unsigned int)f2b(a1) << 16);
        *(unsigned int*)&orow[dp * 2] = packed;
    }
}

// ---------------------------------------------------------------------------
// R20: universal 8-wave (512-thread) GEMM, TN in {64,128}. Block 128 x TN,
// 8 waves as 4x2 (wave tile 32 x TN/2), PK=2 double-buffered global->LDS DMA
// (R3-verified k-seg swizzle), XCD-chunked bijective block swizzle.
//   EPI 0: outp[z*zstride + idx] = bf16(C)   (proj partials)
//   EPI 3: split qkv -> head-major bf16 q/k/v slabs
// ---------------------------------------------------------------------------
template<int EPI, int TN>
__global__ __launch_bounds__(512) void gemm8_kernel(
    const unsigned short* __restrict__ A,   // M x K
    const unsigned short* __restrict__ Bt,  // N x K
    const float* __restrict__ bias,         // N (EPI 2 only)
    unsigned short* __restrict__ outp,      // bf16 partials (EPI 0)
    unsigned short* __restrict__ outb,      // bf16 out (EPI 2)
    unsigned short* __restrict__ outq,      // EPI 3
    unsigned short* __restrict__ outk,      // EPI 3
    unsigned short* __restrict__ outv,      // EPI 3
    int N, int K, int Kslice, size_t zstride, int gx, int gy)
{
    constexpr int PK   = 2;
    constexpr int FN   = TN / 32;             // B frags per wave (2 or 4)
    constexpr int CBCH = TN / 16;             // B 16-row chunks (4 or 8)
    const int tid  = threadIdx.x;
    const int wave = tid >> 6, lane = tid & 63;

    // XCD-chunked bijective swizzle (nwg % 8 == 0 for all our grids)
    const int nwg = gridDim.x;
    const int wg  = (blockIdx.x & 7) * (nwg >> 3) + (blockIdx.x >> 3);
    const int bxi = wg % gx;
    const int byi = (wg / gx) % gy;
    const int bzi = wg / (gx * gy);

    const int bm = byi * 128;
    const int bn = bxi * TN;
    const int wm = (wave >> 1) * 32;          // 4 row-groups of 32
    const int wn = (wave & 1) * (TN / 2);     // 2 col-groups of TN/2
    const int ml = lane & 15, quad = lane >> 4;
    const int kbeg = bzi * Kslice;

    __shared__ unsigned short As[2 * PK][128 * 32];  // 32 KB
    __shared__ unsigned short Bs[2 * PK][TN * 32];   // 16 or 32 KB

    f32x4 acc[2][FN] = {};

    // staging: wave stages A chunk 'wave'; waves < CBCH stage B chunk 'wave'
    const int rr = lane >> 2, ss = lane & 3;
    const int cc = ((ss - (rr >> 1)) & 3) * 8;   // R3-verified swizzle
    const unsigned short* Aa = A + (size_t)(bm + wave * 16 + rr) * K + kbeg + cc;
    const unsigned short* Bb =
        Bt + (size_t)(bn + (wave < CBCH ? wave : 0) * 16 + rr) * K + kbeg + cc;

    const int fslot = ((quad + (ml >> 1)) & 3) * 8;

#pragma unroll
    for (int p = 0; p < PK; p++) {
        load_lds16(Aa + p * 32, &As[p][wave * 512]);
        if (wave < CBCH) load_lds16(Bb + p * 32, &Bs[p][wave * 512]);
    }
    __syncthreads();

    const int steps = Kslice / (32 * PK);
    for (int s = 0; s < steps; s++) {
        const int cb = (s & 1) * PK, nb = cb ^ PK;
        const bool more = (s + 1 < steps);
        if (more) {
#pragma unroll
            for (int p = 0; p < PK; p++) {
                const int k0 = ((s + 1) * PK + p) * 32;
                load_lds16(Aa + k0, &As[nb + p][wave * 512]);
                if (wave < CBCH) load_lds16(Bb + k0, &Bs[nb + p][wave * 512]);
            }
        }

#pragma unroll
        for (int p = 0; p < PK; p++) {
            bf16x8 af[2], bfr[FN];
#pragma unroll
            for (int i = 0; i < 2; i++)
                af[i] = *(const bf16x8*)&As[cb + p][(wm + i * 16 + ml) * 32 + fslot];
#pragma unroll
            for (int j = 0; j < FN; j++)
                bfr[j] = *(const bf16x8*)&Bs[cb + p][(wn + j * 16 + ml) * 32 + fslot];

#pragma unroll
            for (int i = 0; i < 2; i++)
#pragma unroll
                for (int j = 0; j < FN; j++)
                    acc[i][j] = __builtin_amdgcn_mfma_f32_16x16x32_bf16(
                        af[i], bfr[j], acc[i][j], 0, 0, 0);
        }

        if (more) __syncthreads();
    }

    unsigned short* op = outp + (size_t)bzi * zstride;
#pragma unroll
    for (int i = 0; i < 2; i++)
#pragma unroll
        for (int j = 0; j < FN; j++)
#pragma unroll
            for (int r = 0; r < 4; r++) {
                const int row = bm + wm + i * 16 + quad * 4 + r;  // C/D row=quad*4+reg
                const int col = bn + wn + j * 16 + ml;            // C/D col=lane&15
                const float v = acc[i][j][r];
                if (EPI == 0) {
                    op[(size_t)row * N + col] = f2b(v);
                } else if (EPI == 2) {
                    const float u = v + bias[col];
                    const float g = 0.5f * u * (1.0f + fast_erf(u * 0.70710678118654752f));
                    outb[(size_t)row * N + col] = f2b(g);
                } else {
                    // split qkv: col -> (which, head, dim); head-major bf16
                    const int which = col >> 9;
                    const int hh = (col & 511) >> 6;
                    const int dim = col & 63;
                    unsigned short* dst =
                        which == 0 ? outq : (which == 1 ? outk : outv);
                    dst[((size_t)hh * MROWS + row) * HD + dim] = f2b(v);
                }
            }
}

// ---------------------------------------------------------------------------
// R22: 16-wave (1024-thread) GEMM for w1/w2, TN=128 fixed. Same 128x128 tile,
// PK=2 (64 KB LDS), same DMA pattern and barrier count as gemm8 — but grid
// 512 = 2 blocks/CU x 16 waves = 32 waves/CU (hardware max). Requires
// <=64 VGPR/wave (m69 cliff) -> __launch_bounds__(1024, 2); kernel is lean:
// acc[2][2] (16) + af[2]/bfr[2] (16) + ONE staging pointer per wave
// (waves 0-7 stage A chunks, 8-15 stage B chunks; 1 DMA/wave/panel, uniform).
// Wave grid 4x4, wave tile 32x32. Per-output K-order unchanged -> bit-identical.
// ---------------------------------------------------------------------------
template<int EPI>
__global__ __launch_bounds__(1024, 2) void gemm16_kernel(
    const unsigned short* __restrict__ A,   // M x K
    const unsigned short* __restrict__ Bt,  // N x K
    const float* __restrict__ bias,         // N (EPI 2 only)
    unsigned short* __restrict__ outp,      // bf16 partials (EPI 0)
    unsigned short* __restrict__ outb,      // bf16 out (EPI 2)
    int N, int K, int Kslice, size_t zstride, int gx, int gy)
{
    constexpr int PK = 2;
    const int tid  = threadIdx.x;
    const int wave = tid >> 6, lane = tid & 63;   // wave 0..15

    const int nwg = gridDim.x;
    const int wg  = (blockIdx.x & 7) * (nwg >> 3) + (blockIdx.x >> 3);
    const int bxi = wg % gx;
    const int byi = (wg / gx) % gy;
    const int bzi = wg / (gx * gy);

    const int bm = byi * 128;
    const int bn = bxi * 128;
    const int wm = (wave >> 2) * 32;          // 4 row-groups of 32
    const int wn = (wave & 3) * 32;           // 4 col-groups of 32
    const int ml = lane & 15, quad = lane >> 4;
    const int kbeg = bzi * Kslice;

    __shared__ unsigned short As[2 * PK][128 * 32];  // 32 KB
    __shared__ unsigned short Bs[2 * PK][128 * 32];  // 32 KB

    f32x4 acc[2][2] = {};

    // staging: waves 0-7 stage A chunk 'wave'; waves 8-15 stage B chunk 'wave-8'
    const int rr = lane >> 2, ss = lane & 3;
    const int cc = ((ss - (rr >> 1)) & 3) * 8;   // R3-verified swizzle
    const int ch = wave & 7;
    const unsigned short* G = (wave < 8)
        ? A  + (size_t)(bm + ch * 16 + rr) * K + kbeg + cc
        : Bt + (size_t)(bn + ch * 16 + rr) * K + kbeg + cc;

    const int fslot = ((quad + (ml >> 1)) & 3) * 8;

#pragma unroll
    for (int p = 0; p < PK; p++) {
        if (wave < 8) load_lds16(G + p * 32, &As[p][ch * 512]);
        else          load_lds16(G + p * 32, &Bs[p][ch * 512]);
    }
    __syncthreads();

    const int steps = Kslice / (32 * PK);
    for (int s = 0; s < steps; s++) {
        const int cb = (s & 1) * PK, nb = cb ^ PK;
        const bool more = (s + 1 < steps);
        if (more) {
#pragma unroll
            for (int p = 0; p < PK; p++) {
                const int k0 = ((s + 1) * PK + p) * 32;
                if (wave < 8) load_lds16(G + k0, &As[nb + p][ch * 512]);
                else          load_lds16(G + k0, &Bs[nb + p][ch * 512]);
            }
        }

#pragma unroll
        for (int p = 0; p < PK; p++) {
            bf16x8 af[2], bfr[2];
#pragma unroll
            for (int i = 0; i < 2; i++)
                af[i] = *(const bf16x8*)&As[cb + p][(wm + i * 16 + ml) * 32 + fslot];
#pragma unroll
            for (int j = 0; j < 2; j++)
                bfr[j] = *(const bf16x8*)&Bs[cb + p][(wn + j * 16 + ml) * 32 + fslot];

#pragma unroll
            for (int i = 0; i < 2; i++)
#pragma unroll
                for (int j = 0; j < 2; j++)
                    acc[i][j] = __builtin_amdgcn_mfma_f32_16x16x32_bf16(
                        af[i], bfr[j], acc[i][j], 0, 0, 0);
        }

        if (more) __syncthreads();
    }

    unsigned short* op = outp + (size_t)bzi * zstride;
#pragma unroll
    for (int i = 0; i < 2; i++)
#pragma unroll
        for (int j = 0; j < 2; j++)
#pragma unroll
            for (int r = 0; r < 4; r++) {
                const int row = bm + wm + i * 16 + quad * 4 + r;
                const int col = bn + wn + j * 16 + ml;
                const float v = acc[i][j][r];
                if (EPI == 0) {
                    op[(size_t)row * N + col] = f2b(v);
                } else {
                    const float u = v + bias[col];
                    const float g = 0.5f * u * (1.0f + fast_erf(u * 0.70710678118654752f));
                    outb[(size_t)row * N + col] = f2b(g);
                }
            }
}

// ---------------------------------------------------------------------------
// Split-K reduce (bf16 partials, Z slices) + residual + bias, optionally
// fused with the NEXT LayerNorm. One wave per row. In-place xout==xin safe.
// ---------------------------------------------------------------------------
template<bool DO_LN, int Z>
__global__ __launch_bounds__(256) void reduce_kernel(
    const float* __restrict__ xin,
    const unsigned short* __restrict__ part,   // [Z][MROWS x DM] bf16
    const float* __restrict__ bias,            // DM
    const float* __restrict__ lns, const float* __restrict__ lnb,
    float* __restrict__ xout, unsigned short* __restrict__ h)
{
    const int wid  = blockIdx.x * 4 + (threadIdx.x >> 6);
    const int lane = threadIdx.x & 63;
    const int c0 = lane * 4, c1 = 256 + lane * 4;
    const size_t ro = (size_t)wid * DM;

    float4 a0 = *(const float4*)&xin[ro + c0];
    float4 a1 = *(const float4*)&xin[ro + c1];
#pragma unroll
    for (int z = 0; z < Z; z++) {
        const unsigned short* p = part + (size_t)z * (MROWS * (size_t)DM) + ro;
        const ushort4 p0 = *(const ushort4*)&p[c0];
        const ushort4 p1 = *(const ushort4*)&p[c1];
        a0.x += b2f(p0.x); a0.y += b2f(p0.y); a0.z += b2f(p0.z); a0.w += b2f(p0.w);
        a1.x += b2f(p1.x); a1.y += b2f(p1.y); a1.z += b2f(p1.z); a1.w += b2f(p1.w);
    }
    a0.x += bias[c0+0]; a0.y += bias[c0+1]; a0.z += bias[c0+2]; a0.w += bias[c0+3];
    a1.x += bias[c1+0]; a1.y += bias[c1+1]; a1.z += bias[c1+2]; a1.w += bias[c1+3];

    *(float4*)&xout[ro + c0] = a0;
    *(float4*)&xout[ro + c1] = a1;

    if (DO_LN) {
        float s = a0.x + a0.y + a0.z + a0.w + a1.x + a1.y + a1.z + a1.w;
        float q = a0.x*a0.x + a0.y*a0.y + a0.z*a0.z + a0.w*a0.w
                + a1.x*a1.x + a1.y*a1.y + a1.z*a1.z + a1.w*a1.w;
#pragma unroll
        for (int off = 32; off; off >>= 1) {
            s += __shfl_xor(s, off, 64);
            q += __shfl_xor(q, off, 64);
        }
        const float mean = s * (1.0f / DM);
        const float var  = q * (1.0f / DM) - mean * mean;
        const float rs   = rsqrtf(var + 1e-5f);
        unsigned short* hr = h + ro;
        ushort4 o0, o1;
        o0.x = f2b((a0.x - mean) * rs * lns[c0+0] + lnb[c0+0]);
        o0.y = f2b((a0.y - mean) * rs * lns[c0+1] + lnb[c0+1]);
        o0.z = f2b((a0.z - mean) * rs * lns[c0+2] + lnb[c0+2]);
        o0.w = f2b((a0.w - mean) * rs * lns[c0+3] + lnb[c0+3]);
        o1.x = f2b((a1.x - mean) * rs * lns[c1+0] + lnb[c1+0]);
        o1.y = f2b((a1.y - mean) * rs * lns[c1+1] + lnb[c1+1]);
        o1.z = f2b((a1.z - mean) * rs * lns[c1+2] + lnb[c1+2]);
        o1.w = f2b((a1.w - mean) * rs * lns[c1+3] + lnb[c1+3]);
        *(ushort4*)&hr[c0] = o0;
        *(ushort4*)&hr[c1] = o1;
    }
}

// ---------------------------------------------------------------------------
extern "C" void kernel_launch(void* const* d_in, const int* in_sizes, int n_in,
                              void* d_out, int out_size, void* d_ws, size_t ws_size,
                              hipStream_t stream)
{
    (void)in_sizes; (void)n_in; (void)out_size; (void)ws_size;
    const float* x_in   = (const float*)d_in[0];
    const float* ln1_s  = (const float*)d_in[1];
    const float* ln1_b  = (const float*)d_in[2];
    const float* qkv_w  = (const float*)d_in[3];
    const float* proj_w = (const float*)d_in[4];
    const float* proj_b = (const float*)d_in[5];
    const float* ln2_s  = (const float*)d_in[6];
    const float* ln2_b  = (const float*)d_in[7];
    const float* w1     = (const float*)d_in[8];
    const float* b1     = (const float*)d_in[9];
    const float* w2     = (const float*)d_in[10];
    const float* b2     = (const float*)d_in[11];

    // Workspace carve-up (bytes)
    char* ws = (char*)d_ws;
    float*          xbuf = (float*)(ws);                        //   0 MB, 8 MB
    unsigned short* qhb  = (unsigned short*)(ws + 8388608);     //   8 MB, 4 MB bf16 [8][4096][64]
    unsigned short* khb  = (unsigned short*)(ws + 12582912);    //  12 MB, 4 MB
    unsigned short* vhb  = (unsigned short*)(ws + 16777216);    //  16 MB, 4 MB
    unsigned short* ubuf = (unsigned short*)(ws + 33554432);    //  32 MB, 16 MB bf16
    unsigned short* hbuf = (unsigned short*)(ws + 50331648);    //  48 MB, 4 MB
    unsigned short* obuf = (unsigned short*)(ws + 54525952);    //  52 MB, 4 MB
    unsigned short* part = (unsigned short*)(ws + 58720256);    //  56 MB, 16 MB bf16 [4][4096x512]
    unsigned short* qkvT = (unsigned short*)(ws + 92274688);    //  88 MB
    unsigned short* projT= (unsigned short*)(ws + 96993280);
    unsigned short* w1T  = (unsigned short*)(ws + 98566144);
    unsigned short* w2T  = (unsigned short*)(ws + 104857600);   // ends 106 MB

    const size_t ZS = (size_t)MROWS * DM;   // partial-slice stride (elements)

    // All weight transposes + depth-0 LN1 in ONE launch (9216 + 1024 blocks).
    prep_kernel<<<10240, 256, 0, stream>>>(
        qkv_w, proj_w, w1, w2, qkvT, projT, w1T, w2T,
        x_in, ln1_s, ln1_b, hbuf);

    for (int d = 0; d < NDEPTH; d++) {
        const int dil = 1 << d;
        const float* xin = (d == 0) ? x_in : xbuf;   // x residual source

        // qkv = h @ qkv_w -> head-major q/k/v. 8-wave TN=64: 768 blocks = 3/CU.
        gemm8_kernel<3, 64><<<768, 512, 0, stream>>>(
            hbuf, qkvT + (size_t)d * 1536 * 512, nullptr, nullptr, nullptr,
            qhb, khb, vhb, 1536, 512, 512, 0, 24, 32);
        // dilated attention -> o (bf16). 32-query tiles: 1024 blocks = 4/CU.
        attn_kernel<<<2 * NH * (TSEQ / 32), 256, 0, stream>>>(qhb, khb, vhb, obuf, dil);
        // proj partials: split-K x2, Kslice 256. 8-wave TN=64: 512 blocks (8,32,2).
        gemm8_kernel<0, 64><<<512, 512, 0, stream>>>(
            obuf, projT + (size_t)d * 512 * 512, nullptr, part, nullptr,
            nullptr, nullptr, nullptr, 512, 512, 256, ZS, 8, 32);
        // x = xin + sum(part) + proj_b ; h = LN2(x) fused
        reduce_kernel<true, 2><<<MROWS / 4, 256, 0, stream>>>(
            xin, part, proj_b + d * DM, ln2_s + d * DM, ln2_b + d * DM,
            xbuf, hbuf);
        // u = gelu(h @ w1 + b1). 16-wave: 512 blocks x 1024thr = 32 waves/CU.
        gemm16_kernel<2><<<512, 1024, 0, stream>>>(
            hbuf, w1T + (size_t)d * 2048 * 512, b1 + d * 2048, nullptr, ubuf,
            2048, 512, 512, 0, 16, 32);
        // w2 partials: split-K x4, Kslice 512. 16-wave: 512 blocks (4,32,4).
        gemm16_kernel<0><<<512, 1024, 0, stream>>>(
            ubuf, w2T + (size_t)d * 512 * 2048, nullptr, part, nullptr,
            512, 2048, 512, ZS, 4, 32);
        // x += sum(part) + b2 ; fuse next depth's LN1 (or final write to d_out)
        if (d < NDEPTH - 1) {
            reduce_kernel<true, 4><<<MROWS / 4, 256, 0, stream>>>(
                xbuf, part, b2 + d * DM, ln1_s + (d+1) * DM, ln1_b + (d+1) * DM,
                xbuf, hbuf);
        } else {
            reduce_kernel<false, 4><<<MROWS / 4, 256, 0, stream>>>(
                xbuf, part, b2 + d * DM, nullptr, nullptr,
                (float*)d_out, nullptr);
        }
    }
}

// Round 12
// 343.919 us; speedup vs baseline: 1.0088x; 1.0088x over previous
//
#include <hip/hip_runtime.h>
#include <math.h>

// Problem constants (B=2, T=2048, D=512, H=8, hd=64, K=16, DEPTH=3)
#define TSEQ   2048
#define DM     512
#define NH     8
#define HD     64
#define KATT   16
#define NDEPTH 3
#define MROWS  4096   // B*T

typedef __attribute__((ext_vector_type(8))) short bf16x8;
typedef __attribute__((ext_vector_type(8))) unsigned short u16x8;
typedef __attribute__((ext_vector_type(4))) float f32x4;

// f32 -> bf16 (round-to-nearest-even), bit-level
static __device__ __forceinline__ unsigned short f2b(float f) {
    unsigned int u = __float_as_uint(f);
    unsigned int r = (u + 0x7fffu + ((u >> 16) & 1u)) >> 16;
    return (unsigned short)r;
}
// bf16 bits -> f32
static __device__ __forceinline__ float b2f(unsigned short s) {
    return __uint_as_float((unsigned int)s << 16);
}

// global -> LDS direct DMA, 16 B per lane; HW writes lane i at lds + i*16.
static __device__ __forceinline__ void load_lds16(const void* g, void* l) {
    __builtin_amdgcn_global_load_lds(
        (const __attribute__((address_space(1))) unsigned int*)g,
        (__attribute__((address_space(3))) unsigned int*)l, 16, 0, 0);
}

// branchless erf, A&S 7.1.26, |err| <= 1.5e-7
static __device__ __forceinline__ float fast_erf(float x) {
    const float a  = fabsf(x);
    const float t  = 1.0f / (1.0f + 0.3275911f * a);
    const float p  = t * (0.254829592f + t * (-0.284496736f +
                     t * (1.421413741f + t * (-1.453152027f + t * 1.061405429f))));
    const float e  = __expf(-a * a);
    const float r  = 1.0f - p * e;
    return __builtin_copysignf(r, x);
}

// ---------------------------------------------------------------------------
// Prep: ALL weight transposes (f32 [K x N] x3 depth -> bf16 [N x K]) PLUS the
// depth-0 LN1 (x f32 -> hbuf bf16), merged into one launch.
// ---------------------------------------------------------------------------
__global__ __launch_bounds__(256) void prep_kernel(
    const float* __restrict__ qkv_w, const float* __restrict__ proj_w,
    const float* __restrict__ w1,    const float* __restrict__ w2,
    unsigned short* __restrict__ qkvT, unsigned short* __restrict__ projT,
    unsigned short* __restrict__ w1T,  unsigned short* __restrict__ w2T,
    const float* __restrict__ x, const float* __restrict__ sc,
    const float* __restrict__ bi, unsigned short* __restrict__ h)
{
    __shared__ float tile[32][33];
    int id = blockIdx.x;
    const int tid = threadIdx.x;

    if (id < 9216) {
        const float* W; unsigned short* Wt; int Kd, Nd;
        if (id < 2304)      { W = qkv_w;  Wt = qkvT;  Kd = 512;  Nd = 1536; }
        else if (id < 3072) { W = proj_w; Wt = projT; Kd = 512;  Nd = 512;  id -= 2304; }
        else if (id < 6144) { W = w1;     Wt = w1T;   Kd = 512;  Nd = 2048; id -= 3072; }
        else                { W = w2;     Wt = w2T;   Kd = 2048; Nd = 512;  id -= 6144; }
        const int nt = Nd >> 5, per = nt * (Kd >> 5);
        const int d = id / per, rem = id % per;
        const int k0 = (rem / nt) * 32, n0 = (rem % nt) * 32;

        const size_t off = (size_t)d * Kd * Nd;
        const float* Wd = W + off;
        unsigned short* Wtd = Wt + off;
        const int tx = tid & 31, ty = tid >> 5;
#pragma unroll
        for (int r = 0; r < 32; r += 8)
            tile[ty + r][tx] = Wd[(size_t)(k0 + ty + r) * Nd + (n0 + tx)];
        __syncthreads();
#pragma unroll
        for (int r = 0; r < 32; r += 8)
            Wtd[(size_t)(n0 + ty + r) * Kd + (k0 + tx)] = f2b(tile[tx][ty + r]);
        return;
    }

    // ---- LN part ----
    const int wid  = (id - 9216) * 4 + (tid >> 6);
    const int lane = tid & 63;
    const float* xr = x + (size_t)wid * DM;
    const float4 v0 = *(const float4*)&xr[lane * 4];
    const float4 v1 = *(const float4*)&xr[256 + lane * 4];
    float s = v0.x + v0.y + v0.z + v0.w + v1.x + v1.y + v1.z + v1.w;
    float q = v0.x*v0.x + v0.y*v0.y + v0.z*v0.z + v0.w*v0.w
            + v1.x*v1.x + v1.y*v1.y + v1.z*v1.z + v1.w*v1.w;
#pragma unroll
    for (int off = 32; off; off >>= 1) {
        s += __shfl_xor(s, off, 64);
        q += __shfl_xor(q, off, 64);
    }
    const float mean = s * (1.0f / DM);
    const float var  = q * (1.0f / DM) - mean * mean;
    const float rs   = rsqrtf(var + 1e-5f);
    unsigned short* hr = h + (size_t)wid * DM;
    const int c0 = lane * 4, c1 = 256 + lane * 4;
    ushort4 o0, o1;
    o0.x = f2b((v0.x - mean) * rs * sc[c0+0] + bi[c0+0]);
    o0.y = f2b((v0.y - mean) * rs * sc[c0+1] + bi[c0+1]);
    o0.z = f2b((v0.z - mean) * rs * sc[c0+2] + bi[c0+2]);
    o0.w = f2b((v0.w - mean) * rs * sc[c0+3] + bi[c0+3]);
    o1.x = f2b((v1.x - mean) * rs * sc[c1+0] + bi[c1+0]);
    o1.y = f2b((v1.y - mean) * rs * sc[c1+1] + bi[c1+1]);
    o1.z = f2b((v1.z - mean) * rs * sc[c1+2] + bi[c1+2]);
    o1.w = f2b((v1.w - mean) * rs * sc[c1+3] + bi[c1+3]);
    *(ushort4*)&hr[c0] = o0;
    *(ushort4*)&hr[c1] = o1;
}

// ---------------------------------------------------------------------------
// Dilated attention, 32-query tiles (R21), K/V/Q staged in LDS, XCD-chunked
// swizzle, b32 dim-pair phase 2.
// ---------------------------------------------------------------------------
__global__ __launch_bounds__(256) void attn_kernel(
    const unsigned short* __restrict__ qh, const unsigned short* __restrict__ kh,
    const unsigned short* __restrict__ vh, unsigned short* __restrict__ o, int dil)
{
    const int nwg = gridDim.x;                         // 1024, %8 == 0
    const int wg  = (blockIdx.x & 7) * (nwg >> 3) + (blockIdx.x >> 3);
    const int tile = wg & (TSEQ / 32 - 1);   // 64 query tiles of 32
    const int bh   = wg >> 6;
    const int b    = bh >> 3, hh = bh & 7;
    const int t0   = tile * 32;
    const int tid  = threadIdx.x;
    const int wave = tid >> 6, lane = tid & 63;
    const int s    = lane & 15;               // key slot 0..15
    const size_t slab = ((size_t)hh * MROWS + (size_t)b * TSEQ) * HD;

    const int R    = 15 * dil + 32;           // staged rows: 47 / 62 / 92
    const int base = t0 - 15 * dil;

    __shared__ unsigned short ks[92 * 64];
    __shared__ unsigned short vs[92 * 64];
    __shared__ unsigned short qs[32 * 64];
    __shared__ float p_lds[32][17];

    // ---- stage K/V rows [base, base+R) (row-0-clamped) + Q tile ----
    for (int c = tid; c < R * 8; c += 256) {
        const int r = c >> 3, cs = c & 7;
        const int sr = max(base + r, 0);      // clamped rows get weight 0 later
        const int ps = ((cs + r + (r >> 2)) & 7) * 8;
        const size_t g = slab + (size_t)sr * HD + cs * 8;
        *(u16x8*)&ks[r * 64 + ps] = *(const u16x8*)(kh + g);
        *(u16x8*)&vs[r * 64 + ps] = *(const u16x8*)(vh + g);
    }
    {   // Q: 32 rows x 8 chunks = 256 = one chunk per thread
        const int r = tid >> 3, cs = tid & 7;
        *(u16x8*)&qs[r * 64 + cs * 8] =
            *(const u16x8*)(qh + slab + (size_t)(t0 + r) * HD + cs * 8);
    }
    __syncthreads();

    // ---- phase 1: scores + softmax; 2 (q, slot) pairs per lane ----
#pragma unroll
    for (int qi = 0; qi < 2; qi++) {
        const int tq = wave * 8 + qi * 4 + (lane >> 4);   // query 0..31
        const int t  = t0 + tq;
        const bool valid = (t - s * dil) >= 0;
        const int  kidx  = tq + 15 * dil - s * dil;       // staged index
        float dot = 0.0f;
#pragma unroll
        for (int j = 0; j < 8; j++) {
            const u16x8 kk = *(const u16x8*)&ks[kidx * 64 + (((j + kidx + (kidx >> 2)) & 7) * 8)];
            const u16x8 qq = *(const u16x8*)&qs[tq * 64 + j * 8];
#pragma unroll
            for (int e = 0; e < 8; e++) dot += b2f(qq[e]) * b2f(kk[e]);
        }
        const float sc = valid ? dot * 0.125f : -1e30f;
        float m = sc;
#pragma unroll
        for (int off = 1; off < 16; off <<= 1) m = fmaxf(m, __shfl_xor(m, off, 64));
        const float p = expf(sc - m);
        float l = p;
#pragma unroll
        for (int off = 1; off < 16; off <<= 1) l += __shfl_xor(l, off, 64);
        p_lds[tq][s] = p / l;
    }
    __syncthreads();

    // ---- phase 2: o = sum_s p * v ; 32 lanes x 2 dims, 4 q-iterations ----
    const int dp  = lane & 31;                // dim-pair index: dims 2dp, 2dp+1
    const int qh2 = lane >> 5;                // 0/1
#pragma unroll
    for (int qi = 0; qi < 4; qi++) {
        const int qq = qi * 8 + wave * 2 + qh2;           // query 0..31
        float a0 = 0.0f, a1 = 0.0f;
#pragma unroll
        for (int ss = 0; ss < KATT; ss++) {
            const int idx = qq + 15 * dil - ss * dil;     // staged V row
            const float pw = p_lds[qq][ss];               // exactly 0 for masked slots
            const int ch = ((dp >> 2) + idx + (idx >> 2)) & 7;
            const unsigned int vv =
                *(const unsigned int*)&vs[idx * 64 + ch * 8 + (dp & 3) * 2];
            a0 += pw * b2f((unsigned short)(vv & 0xffffu));
            a1 += pw * b2f((unsigned short)(vv >> 16));
        }
        unsigned short* orow = o + (size_t)(b * TSEQ + (t0 + qq)) * DM + (size_t)hh * HD;
        const unsigned int packed = (unsigned int)f2b(a0) | ((unsigned int)f2b(a1) << 16);
        *(unsigned int*)&orow[dp * 2] = packed;
    }
}

// ---------------------------------------------------------------------------
// R20: universal 8-wave (512-thread) GEMM, TN in {64,128}. Block 128 x TN,
// 8 waves as 4x2 (wave tile 32 x TN/2), PK=2 double-buffered global->LDS DMA
// (R3-verified k-seg swizzle), XCD-chunked bijective block swizzle.
// R23: EPI 0/2 epilogues pack adjacent-column pairs into u32 stores via one
// __shfl_xor(.,1): even lanes store row r0 of the pair, odd lanes row r1 —
// same bytes, half the store instructions, 4 B/lane. EPI 3 (qkv scatter)
// unchanged (proven path).
//   EPI 0: outp[z*zstride + idx] = bf16(C)   (proj/w2 partials)
//   EPI 2: outb = bf16(gelu(C + bias))       (w1)
//   EPI 3: split qkv -> head-major bf16 q/k/v slabs
// ---------------------------------------------------------------------------
template<int EPI, int TN>
__global__ __launch_bounds__(512) void gemm8_kernel(
    const unsigned short* __restrict__ A,   // M x K
    const unsigned short* __restrict__ Bt,  // N x K
    const float* __restrict__ bias,         // N (EPI 2 only)
    unsigned short* __restrict__ outp,      // bf16 partials (EPI 0)
    unsigned short* __restrict__ outb,      // bf16 out (EPI 2)
    unsigned short* __restrict__ outq,      // EPI 3
    unsigned short* __restrict__ outk,      // EPI 3
    unsigned short* __restrict__ outv,      // EPI 3
    int N, int K, int Kslice, size_t zstride, int gx, int gy)
{
    constexpr int PK   = 2;
    constexpr int FN   = TN / 32;             // B frags per wave (2 or 4)
    constexpr int CBCH = TN / 16;             // B 16-row chunks (4 or 8)
    const int tid  = threadIdx.x;
    const int wave = tid >> 6, lane = tid & 63;

    // XCD-chunked bijective swizzle (nwg % 8 == 0 for all our grids)
    const int nwg = gridDim.x;
    const int wg  = (blockIdx.x & 7) * (nwg >> 3) + (blockIdx.x >> 3);
    const int bxi = wg % gx;
    const int byi = (wg / gx) % gy;
    const int bzi = wg / (gx * gy);

    const int bm = byi * 128;
    const int bn = bxi * TN;
    const int wm = (wave >> 1) * 32;          // 4 row-groups of 32
    const int wn = (wave & 1) * (TN / 2);     // 2 col-groups of TN/2
    const int ml = lane & 15, quad = lane >> 4;
    const int kbeg = bzi * Kslice;

    __shared__ unsigned short As[2 * PK][128 * 32];  // 32 KB
    __shared__ unsigned short Bs[2 * PK][TN * 32];   // 16 or 32 KB

    f32x4 acc[2][FN] = {};

    // staging: wave stages A chunk 'wave'; waves < CBCH stage B chunk 'wave'
    const int rr = lane >> 2, ss = lane & 3;
    const int cc = ((ss - (rr >> 1)) & 3) * 8;   // R3-verified swizzle
    const unsigned short* Aa = A + (size_t)(bm + wave * 16 + rr) * K + kbeg + cc;
    const unsigned short* Bb =
        Bt + (size_t)(bn + (wave < CBCH ? wave : 0) * 16 + rr) * K + kbeg + cc;

    const int fslot = ((quad + (ml >> 1)) & 3) * 8;

#pragma unroll
    for (int p = 0; p < PK; p++) {
        load_lds16(Aa + p * 32, &As[p][wave * 512]);
        if (wave < CBCH) load_lds16(Bb + p * 32, &Bs[p][wave * 512]);
    }
    __syncthreads();

    const int steps = Kslice / (32 * PK);
    for (int s = 0; s < steps; s++) {
        const int cb = (s & 1) * PK, nb = cb ^ PK;
        const bool more = (s + 1 < steps);
        if (more) {
#pragma unroll
            for (int p = 0; p < PK; p++) {
                const int k0 = ((s + 1) * PK + p) * 32;
                load_lds16(Aa + k0, &As[nb + p][wave * 512]);
                if (wave < CBCH) load_lds16(Bb + k0, &Bs[nb + p][wave * 512]);
            }
        }

#pragma unroll
        for (int p = 0; p < PK; p++) {
            bf16x8 af[2], bfr[FN];
#pragma unroll
            for (int i = 0; i < 2; i++)
                af[i] = *(const bf16x8*)&As[cb + p][(wm + i * 16 + ml) * 32 + fslot];
#pragma unroll
            for (int j = 0; j < FN; j++)
                bfr[j] = *(const bf16x8*)&Bs[cb + p][(wn + j * 16 + ml) * 32 + fslot];

#pragma unroll
            for (int i = 0; i < 2; i++)
#pragma unroll
                for (int j = 0; j < FN; j++)
                    acc[i][j] = __builtin_amdgcn_mfma_f32_16x16x32_bf16(
                        af[i], bfr[j], acc[i][j], 0, 0, 0);
        }

        if (more) __syncthreads();
    }

    unsigned short* op = outp + (size_t)bzi * zstride;
    if (EPI == 3) {
#pragma unroll
        for (int i = 0; i < 2; i++)
#pragma unroll
            for (int j = 0; j < FN; j++)
#pragma unroll
                for (int r = 0; r < 4; r++) {
                    const int row = bm + wm + i * 16 + quad * 4 + r;
                    const int col = bn + wn + j * 16 + ml;
                    const int which = col >> 9;
                    const int hh = (col & 511) >> 6;
                    const int dim = col & 63;
                    unsigned short* dst =
                        which == 0 ? outq : (which == 1 ? outk : outv);
                    dst[((size_t)hh * MROWS + row) * HD + dim] = f2b(acc[i][j][r]);
                }
    } else {
        // paired-column u32 stores (R23): even lanes store row r0, odd row r1
        const bool even = (ml & 1) == 0;
        unsigned short* dst = (EPI == 0) ? op : outb;
#pragma unroll
        for (int i = 0; i < 2; i++)
#pragma unroll
            for (int j = 0; j < FN; j++)
#pragma unroll
                for (int rp = 0; rp < 2; rp++) {
                    const int r0 = rp * 2, r1 = rp * 2 + 1;
                    float v0 = acc[i][j][r0], v1 = acc[i][j][r1];
                    unsigned short m0, m1;
                    if (EPI == 2) {
                        const int col = bn + wn + j * 16 + ml;
                        const float u0 = v0 + bias[col];
                        const float u1 = v1 + bias[col];
                        m0 = f2b(0.5f * u0 * (1.0f + fast_erf(u0 * 0.70710678118654752f)));
                        m1 = f2b(0.5f * u1 * (1.0f + fast_erf(u1 * 0.70710678118654752f)));
                    } else {
                        m0 = f2b(v0); m1 = f2b(v1);
                    }
                    const unsigned int o0 = (unsigned int)__shfl_xor((int)m0, 1, 64);
                    const unsigned int o1 = (unsigned int)__shfl_xor((int)m1, 1, 64);
                    const int colp = bn + wn + j * 16 + (ml & ~1);
                    const int row  = bm + wm + i * 16 + quad * 4 + (even ? r0 : r1);
                    const unsigned int word = even
                        ? ((unsigned int)m0 | (o0 << 16))    // (r0: my col, partner col+1)
                        : (o1 | ((unsigned int)m1 << 16));   // (r1: partner col, my col+1)
                    *(unsigned int*)&dst[(size_t)row * N + colp] = word;
                }
    }
}

// ---------------------------------------------------------------------------
// Split-K reduce (bf16 partials, Z slices) + residual + bias, optionally
// fused with the NEXT LayerNorm. One wave per row. In-place xout==xin safe.
// ---------------------------------------------------------------------------
template<bool DO_LN, int Z>
__global__ __launch_bounds__(256) void reduce_kernel(
    const float* __restrict__ xin,
    const unsigned short* __restrict__ part,   // [Z][MROWS x DM] bf16
    const float* __restrict__ bias,            // DM
    const float* __restrict__ lns, const float* __restrict__ lnb,
    float* __restrict__ xout, unsigned short* __restrict__ h)
{
    const int wid  = blockIdx.x * 4 + (threadIdx.x >> 6);
    const int lane = threadIdx.x & 63;
    const int c0 = lane * 4, c1 = 256 + lane * 4;
    const size_t ro = (size_t)wid * DM;

    float4 a0 = *(const float4*)&xin[ro + c0];
    float4 a1 = *(const float4*)&xin[ro + c1];
#pragma unroll
    for (int z = 0; z < Z; z++) {
        const unsigned short* p = part + (size_t)z * (MROWS * (size_t)DM) + ro;
        const ushort4 p0 = *(const ushort4*)&p[c0];
        const ushort4 p1 = *(const ushort4*)&p[c1];
        a0.x += b2f(p0.x); a0.y += b2f(p0.y); a0.z += b2f(p0.z); a0.w += b2f(p0.w);
        a1.x += b2f(p1.x); a1.y += b2f(p1.y); a1.z += b2f(p1.z); a1.w += b2f(p1.w);
    }
    a0.x += bias[c0+0]; a0.y += bias[c0+1]; a0.z += bias[c0+2]; a0.w += bias[c0+3];
    a1.x += bias[c1+0]; a1.y += bias[c1+1]; a1.z += bias[c1+2]; a1.w += bias[c1+3];

    *(float4*)&xout[ro + c0] = a0;
    *(float4*)&xout[ro + c1] = a1;

    if (DO_LN) {
        float s = a0.x + a0.y + a0.z + a0.w + a1.x + a1.y + a1.z + a1.w;
        float q = a0.x*a0.x + a0.y*a0.y + a0.z*a0.z + a0.w*a0.w
                + a1.x*a1.x + a1.y*a1.y + a1.z*a1.z + a1.w*a1.w;
#pragma unroll
        for (int off = 32; off; off >>= 1) {
            s += __shfl_xor(s, off, 64);
            q += __shfl_xor(q, off, 64);
        }
        const float mean = s * (1.0f / DM);
        const float var  = q * (1.0f / DM) - mean * mean;
        const float rs   = rsqrtf(var + 1e-5f);
        unsigned short* hr = h + ro;
        ushort4 o0, o1;
        o0.x = f2b((a0.x - mean) * rs * lns[c0+0] + lnb[c0+0]);
        o0.y = f2b((a0.y - mean) * rs * lns[c0+1] + lnb[c0+1]);
        o0.z = f2b((a0.z - mean) * rs * lns[c0+2] + lnb[c0+2]);
        o0.w = f2b((a0.w - mean) * rs * lns[c0+3] + lnb[c0+3]);
        o1.x = f2b((a1.x - mean) * rs * lns[c1+0] + lnb[c1+0]);
        o1.y = f2b((a1.y - mean) * rs * lns[c1+1] + lnb[c1+1]);
        o1.z = f2b((a1.z - mean) * rs * lns[c1+2] + lnb[c1+2]);
        o1.w = f2b((a1.w - mean) * rs * lns[c1+3] + lnb[c1+3]);
        *(ushort4*)&hr[c0] = o0;
        *(ushort4*)&hr[c1] = o1;
    }
}

// ---------------------------------------------------------------------------
extern "C" void kernel_launch(void* const* d_in, const int* in_sizes, int n_in,
                              void* d_out, int out_size, void* d_ws, size_t ws_size,
                              hipStream_t stream)
{
    (void)in_sizes; (void)n_in; (void)out_size; (void)ws_size;
    const float* x_in   = (const float*)d_in[0];
    const float* ln1_s  = (const float*)d_in[1];
    const float* ln1_b  = (const float*)d_in[2];
    const float* qkv_w  = (const float*)d_in[3];
    const float* proj_w = (const float*)d_in[4];
    const float* proj_b = (const float*)d_in[5];
    const float* ln2_s  = (const float*)d_in[6];
    const float* ln2_b  = (const float*)d_in[7];
    const float* w1     = (const float*)d_in[8];
    const float* b1     = (const float*)d_in[9];
    const float* w2     = (const float*)d_in[10];
    const float* b2     = (const float*)d_in[11];

    // Workspace carve-up (bytes)
    char* ws = (char*)d_ws;
    float*          xbuf = (float*)(ws);                        //   0 MB, 8 MB
    unsigned short* qhb  = (unsigned short*)(ws + 8388608);     //   8 MB, 4 MB bf16 [8][4096][64]
    unsigned short* khb  = (unsigned short*)(ws + 12582912);    //  12 MB, 4 MB
    unsigned short* vhb  = (unsigned short*)(ws + 16777216);    //  16 MB, 4 MB
    unsigned short* ubuf = (unsigned short*)(ws + 33554432);    //  32 MB, 16 MB bf16
    unsigned short* hbuf = (unsigned short*)(ws + 50331648);    //  48 MB, 4 MB
    unsigned short* obuf = (unsigned short*)(ws + 54525952);    //  52 MB, 4 MB
    unsigned short* part = (unsigned short*)(ws + 58720256);    //  56 MB, 16 MB bf16 [4][4096x512]
    unsigned short* qkvT = (unsigned short*)(ws + 92274688);    //  88 MB
    unsigned short* projT= (unsigned short*)(ws + 96993280);
    unsigned short* w1T  = (unsigned short*)(ws + 98566144);
    unsigned short* w2T  = (unsigned short*)(ws + 104857600);   // ends 106 MB

    const size_t ZS = (size_t)MROWS * DM;   // partial-slice stride (elements)

    // All weight transposes + depth-0 LN1 in ONE launch (9216 + 1024 blocks).
    prep_kernel<<<10240, 256, 0, stream>>>(
        qkv_w, proj_w, w1, w2, qkvT, projT, w1T, w2T,
        x_in, ln1_s, ln1_b, hbuf);

    for (int d = 0; d < NDEPTH; d++) {
        const int dil = 1 << d;
        const float* xin = (d == 0) ? x_in : xbuf;   // x residual source

        // qkv = h @ qkv_w -> head-major q/k/v. 8-wave TN=64: 768 blocks = 3/CU.
        gemm8_kernel<3, 64><<<768, 512, 0, stream>>>(
            hbuf, qkvT + (size_t)d * 1536 * 512, nullptr, nullptr, nullptr,
            qhb, khb, vhb, 1536, 512, 512, 0, 24, 32);
        // dilated attention -> o (bf16). 32-query tiles: 1024 blocks = 4/CU.
        attn_kernel<<<2 * NH * (TSEQ / 32), 256, 0, stream>>>(qhb, khb, vhb, obuf, dil);
        // proj partials: split-K x2, Kslice 256. 8-wave TN=64: 512 blocks (8,32,2).
        gemm8_kernel<0, 64><<<512, 512, 0, stream>>>(
            obuf, projT + (size_t)d * 512 * 512, nullptr, part, nullptr,
            nullptr, nullptr, nullptr, 512, 512, 256, ZS, 8, 32);
        // x = xin + sum(part) + proj_b ; h = LN2(x) fused
        reduce_kernel<true, 2><<<MROWS / 4, 256, 0, stream>>>(
            xin, part, proj_b + d * DM, ln2_s + d * DM, ln2_b + d * DM,
            xbuf, hbuf);
        // u = gelu(h @ w1 + b1). 8-wave TN=128: 512 blocks (16,32).
        gemm8_kernel<2, 128><<<512, 512, 0, stream>>>(
            hbuf, w1T + (size_t)d * 2048 * 512, b1 + d * 2048, nullptr, ubuf,
            nullptr, nullptr, nullptr, 2048, 512, 512, 0, 16, 32);
        // w2 partials: split-K x4, Kslice 512. 8-wave TN=128: 512 blocks (4,32,4).
        gemm8_kernel<0, 128><<<512, 512, 0, stream>>>(
            ubuf, w2T + (size_t)d * 512 * 2048, nullptr, part, nullptr,
            nullptr, nullptr, nullptr, 512, 2048, 512, ZS, 4, 32);
        // x += sum(part) + b2 ; fuse next depth's LN1 (or final write to d_out)
        if (d < NDEPTH - 1) {
            reduce_kernel<true, 4><<<MROWS / 4, 256, 0, stream>>>(
                xbuf, part, b2 + d * DM, ln1_s + (d+1) * DM, ln1_b + (d+1) * DM,
                xbuf, hbuf);
        } else {
            reduce_kernel<false, 4><<<MROWS / 4, 256, 0, stream>>>(
                xbuf, part, b2 + d * DM, nullptr, nullptr,
                (float*)d_out, nullptr);
        }
    }
}

// Round 13
// 328.310 us; speedup vs baseline: 1.0568x; 1.0475x over previous
//
#include <hip/hip_runtime.h>
#include <math.h>

// Problem constants (B=2, T=2048, D=512, H=8, hd=64, K=16, DEPTH=3)
#define TSEQ   2048
#define DM     512
#define NH     8
#define HD     64
#define KATT   16
#define NDEPTH 3
#define MROWS  4096   // B*T

typedef __attribute__((ext_vector_type(8))) short bf16x8;
typedef __attribute__((ext_vector_type(8))) unsigned short u16x8;
typedef __attribute__((ext_vector_type(4))) float f32x4;

// f32 -> bf16 (round-to-nearest-even), bit-level
static __device__ __forceinline__ unsigned short f2b(float f) {
    unsigned int u = __float_as_uint(f);
    unsigned int r = (u + 0x7fffu + ((u >> 16) & 1u)) >> 16;
    return (unsigned short)r;
}
// bf16 bits -> f32
static __device__ __forceinline__ float b2f(unsigned short s) {
    return __uint_as_float((unsigned int)s << 16);
}

// global -> LDS direct DMA, 16 B per lane; HW writes lane i at lds + i*16.
static __device__ __forceinline__ void load_lds16(const void* g, void* l) {
    __builtin_amdgcn_global_load_lds(
        (const __attribute__((address_space(1))) unsigned int*)g,
        (__attribute__((address_space(3))) unsigned int*)l, 16, 0, 0);
}

// branchless erf, A&S 7.1.26, |err| <= 1.5e-7
static __device__ __forceinline__ float fast_erf(float x) {
    const float a  = fabsf(x);
    const float t  = 1.0f / (1.0f + 0.3275911f * a);
    const float p  = t * (0.254829592f + t * (-0.284496736f +
                     t * (1.421413741f + t * (-1.453152027f + t * 1.061405429f))));
    const float e  = __expf(-a * a);
    const float r  = 1.0f - p * e;
    return __builtin_copysignf(r, x);
}

// ---------------------------------------------------------------------------
// Prep: ALL weight transposes (f32 [K x N] x3 depth -> bf16 [N x K]) PLUS the
// depth-0 LN1 (x f32 -> hbuf bf16), merged into one launch.
// ---------------------------------------------------------------------------
__global__ __launch_bounds__(256) void prep_kernel(
    const float* __restrict__ qkv_w, const float* __restrict__ proj_w,
    const float* __restrict__ w1,    const float* __restrict__ w2,
    unsigned short* __restrict__ qkvT, unsigned short* __restrict__ projT,
    unsigned short* __restrict__ w1T,  unsigned short* __restrict__ w2T,
    const float* __restrict__ x, const float* __restrict__ sc,
    const float* __restrict__ bi, unsigned short* __restrict__ h)
{
    __shared__ float tile[32][33];
    int id = blockIdx.x;
    const int tid = threadIdx.x;

    if (id < 9216) {
        const float* W; unsigned short* Wt; int Kd, Nd;
        if (id < 2304)      { W = qkv_w;  Wt = qkvT;  Kd = 512;  Nd = 1536; }
        else if (id < 3072) { W = proj_w; Wt = projT; Kd = 512;  Nd = 512;  id -= 2304; }
        else if (id < 6144) { W = w1;     Wt = w1T;   Kd = 512;  Nd = 2048; id -= 3072; }
        else                { W = w2;     Wt = w2T;   Kd = 2048; Nd = 512;  id -= 6144; }
        const int nt = Nd >> 5, per = nt * (Kd >> 5);
        const int d = id / per, rem = id % per;
        const int k0 = (rem / nt) * 32, n0 = (rem % nt) * 32;

        const size_t off = (size_t)d * Kd * Nd;
        const float* Wd = W + off;
        unsigned short* Wtd = Wt + off;
        const int tx = tid & 31, ty = tid >> 5;
#pragma unroll
        for (int r = 0; r < 32; r += 8)
            tile[ty + r][tx] = Wd[(size_t)(k0 + ty + r) * Nd + (n0 + tx)];
        __syncthreads();
#pragma unroll
        for (int r = 0; r < 32; r += 8)
            Wtd[(size_t)(n0 + ty + r) * Kd + (k0 + tx)] = f2b(tile[tx][ty + r]);
        return;
    }

    // ---- LN part ----
    const int wid  = (id - 9216) * 4 + (tid >> 6);
    const int lane = tid & 63;
    const float* xr = x + (size_t)wid * DM;
    const float4 v0 = *(const float4*)&xr[lane * 4];
    const float4 v1 = *(const float4*)&xr[256 + lane * 4];
    float s = v0.x + v0.y + v0.z + v0.w + v1.x + v1.y + v1.z + v1.w;
    float q = v0.x*v0.x + v0.y*v0.y + v0.z*v0.z + v0.w*v0.w
            + v1.x*v1.x + v1.y*v1.y + v1.z*v1.z + v1.w*v1.w;
#pragma unroll
    for (int off = 32; off; off >>= 1) {
        s += __shfl_xor(s, off, 64);
        q += __shfl_xor(q, off, 64);
    }
    const float mean = s * (1.0f / DM);
    const float var  = q * (1.0f / DM) - mean * mean;
    const float rs   = rsqrtf(var + 1e-5f);
    unsigned short* hr = h + (size_t)wid * DM;
    const int c0 = lane * 4, c1 = 256 + lane * 4;
    ushort4 o0, o1;
    o0.x = f2b((v0.x - mean) * rs * sc[c0+0] + bi[c0+0]);
    o0.y = f2b((v0.y - mean) * rs * sc[c0+1] + bi[c0+1]);
    o0.z = f2b((v0.z - mean) * rs * sc[c0+2] + bi[c0+2]);
    o0.w = f2b((v0.w - mean) * rs * sc[c0+3] + bi[c0+3]);
    o1.x = f2b((v1.x - mean) * rs * sc[c1+0] + bi[c1+0]);
    o1.y = f2b((v1.y - mean) * rs * sc[c1+1] + bi[c1+1]);
    o1.z = f2b((v1.z - mean) * rs * sc[c1+2] + bi[c1+2]);
    o1.w = f2b((v1.w - mean) * rs * sc[c1+3] + bi[c1+3]);
    *(ushort4*)&hr[c0] = o0;
    *(ushort4*)&hr[c1] = o1;
}

// ---------------------------------------------------------------------------
// Dilated attention, 32-query tiles (R21), K/V/Q staged in LDS, XCD-chunked
// swizzle, b32 dim-pair phase 2.
// ---------------------------------------------------------------------------
__global__ __launch_bounds__(256) void attn_kernel(
    const unsigned short* __restrict__ qh, const unsigned short* __restrict__ kh,
    const unsigned short* __restrict__ vh, unsigned short* __restrict__ o, int dil)
{
    const int nwg = gridDim.x;                         // 1024, %8 == 0
    const int wg  = (blockIdx.x & 7) * (nwg >> 3) + (blockIdx.x >> 3);
    const int tile = wg & (TSEQ / 32 - 1);   // 64 query tiles of 32
    const int bh   = wg >> 6;
    const int b    = bh >> 3, hh = bh & 7;
    const int t0   = tile * 32;
    const int tid  = threadIdx.x;
    const int wave = tid >> 6, lane = tid & 63;
    const int s    = lane & 15;               // key slot 0..15
    const size_t slab = ((size_t)hh * MROWS + (size_t)b * TSEQ) * HD;

    const int R    = 15 * dil + 32;           // staged rows: 47 / 62 / 92
    const int base = t0 - 15 * dil;

    __shared__ unsigned short ks[92 * 64];
    __shared__ unsigned short vs[92 * 64];
    __shared__ unsigned short qs[32 * 64];
    __shared__ float p_lds[32][17];

    // ---- stage K/V rows [base, base+R) (row-0-clamped) + Q tile ----
    for (int c = tid; c < R * 8; c += 256) {
        const int r = c >> 3, cs = c & 7;
        const int sr = max(base + r, 0);      // clamped rows get weight 0 later
        const int ps = ((cs + r + (r >> 2)) & 7) * 8;
        const size_t g = slab + (size_t)sr * HD + cs * 8;
        *(u16x8*)&ks[r * 64 + ps] = *(const u16x8*)(kh + g);
        *(u16x8*)&vs[r * 64 + ps] = *(const u16x8*)(vh + g);
    }
    {   // Q: 32 rows x 8 chunks = 256 = one chunk per thread
        const int r = tid >> 3, cs = tid & 7;
        *(u16x8*)&qs[r * 64 + cs * 8] =
            *(const u16x8*)(qh + slab + (size_t)(t0 + r) * HD + cs * 8);
    }
    __syncthreads();

    // ---- phase 1: scores + softmax; 2 (q, slot) pairs per lane ----
#pragma unroll
    for (int qi = 0; qi < 2; qi++) {
        const int tq = wave * 8 + qi * 4 + (lane >> 4);   // query 0..31
        const int t  = t0 + tq;
        const bool valid = (t - s * dil) >= 0;
        const int  kidx  = tq + 15 * dil - s * dil;       // staged index
        float dot = 0.0f;
#pragma unroll
        for (int j = 0; j < 8; j++) {
            const u16x8 kk = *(const u16x8*)&ks[kidx * 64 + (((j + kidx + (kidx >> 2)) & 7) * 8)];
            const u16x8 qq = *(const u16x8*)&qs[tq * 64 + j * 8];
#pragma unroll
            for (int e = 0; e < 8; e++) dot += b2f(qq[e]) * b2f(kk[e]);
        }
        const float sc = valid ? dot * 0.125f : -1e30f;
        float m = sc;
#pragma unroll
        for (int off = 1; off < 16; off <<= 1) m = fmaxf(m, __shfl_xor(m, off, 64));
        const float p = expf(sc - m);
        float l = p;
#pragma unroll
        for (int off = 1; off < 16; off <<= 1) l += __shfl_xor(l, off, 64);
        p_lds[tq][s] = p / l;
    }
    __syncthreads();

    // ---- phase 2: o = sum_s p * v ; 32 lanes x 2 dims, 4 q-iterations ----
    const int dp  = lane & 31;                // dim-pair index: dims 2dp, 2dp+1
    const int qh2 = lane >> 5;                // 0/1
#pragma unroll
    for (int qi = 0; qi < 4; qi++) {
        const int qq = qi * 8 + wave * 2 + qh2;           // query 0..31
        float a0 = 0.0f, a1 = 0.0f;
#pragma unroll
        for (int ss = 0; ss < KATT; ss++) {
            const int idx = qq + 15 * dil - ss * dil;     // staged V row
            const float pw = p_lds[qq][ss];               // exactly 0 for masked slots
            const int ch = ((dp >> 2) + idx + (idx >> 2)) & 7;
            const unsigned int vv =
                *(const unsigned int*)&vs[idx * 64 + ch * 8 + (dp & 3) * 2];
            a0 += pw * b2f((unsigned short)(vv & 0xffffu));
            a1 += pw * b2f((unsigned short)(vv >> 16));
        }
        unsigned short* orow = o + (size_t)(b * TSEQ + (t0 + qq)) * DM + (size_t)hh * HD;
        const unsigned int packed = (unsigned int)f2b(a0) | ((unsigned int)f2b(a1) << 16);
        *(unsigned int*)&orow[dp * 2] = packed;
    }
}

// ---------------------------------------------------------------------------
// R20: universal 8-wave (512-thread) GEMM, TN in {64,128}. Block 128 x TN,
// 8 waves as 4x2 (wave tile 32 x TN/2), PK=2 double-buffered global->LDS DMA
// (R3-verified k-seg swizzle), XCD-chunked bijective block swizzle.
// Mechanism (R2->R6 proven): same tile / traffic / barrier count as the
// 4-wave version but 2x waves per CU to hide the per-step vmcnt(0) drain.
//   EPI 0: outp[z*zstride + idx] = bf16(C)   (proj/w2 partials)
//   EPI 2: outb = bf16(gelu(C + bias))       (w1)
//   EPI 3: split qkv -> head-major bf16 q/k/v slabs
// ---------------------------------------------------------------------------
template<int EPI, int TN>
__global__ __launch_bounds__(512) void gemm8_kernel(
    const unsigned short* __restrict__ A,   // M x K
    const unsigned short* __restrict__ Bt,  // N x K
    const float* __restrict__ bias,         // N (EPI 2 only)
    unsigned short* __restrict__ outp,      // bf16 partials (EPI 0)
    unsigned short* __restrict__ outb,      // bf16 out (EPI 2)
    unsigned short* __restrict__ outq,      // EPI 3
    unsigned short* __restrict__ outk,      // EPI 3
    unsigned short* __restrict__ outv,      // EPI 3
    int N, int K, int Kslice, size_t zstride, int gx, int gy)
{
    constexpr int PK   = 2;
    constexpr int FN   = TN / 32;             // B frags per wave (2 or 4)
    constexpr int CBCH = TN / 16;             // B 16-row chunks (4 or 8)
    const int tid  = threadIdx.x;
    const int wave = tid >> 6, lane = tid & 63;

    // XCD-chunked bijective swizzle (nwg % 8 == 0 for all our grids)
    const int nwg = gridDim.x;
    const int wg  = (blockIdx.x & 7) * (nwg >> 3) + (blockIdx.x >> 3);
    const int bxi = wg % gx;
    const int byi = (wg / gx) % gy;
    const int bzi = wg / (gx * gy);

    const int bm = byi * 128;
    const int bn = bxi * TN;
    const int wm = (wave >> 1) * 32;          // 4 row-groups of 32
    const int wn = (wave & 1) * (TN / 2);     // 2 col-groups of TN/2
    const int ml = lane & 15, quad = lane >> 4;
    const int kbeg = bzi * Kslice;

    __shared__ unsigned short As[2 * PK][128 * 32];  // 32 KB
    __shared__ unsigned short Bs[2 * PK][TN * 32];   // 16 or 32 KB

    f32x4 acc[2][FN] = {};

    // staging: wave stages A chunk 'wave'; waves < CBCH stage B chunk 'wave'
    const int rr = lane >> 2, ss = lane & 3;
    const int cc = ((ss - (rr >> 1)) & 3) * 8;   // R3-verified swizzle
    const unsigned short* Aa = A + (size_t)(bm + wave * 16 + rr) * K + kbeg + cc;
    const unsigned short* Bb =
        Bt + (size_t)(bn + (wave < CBCH ? wave : 0) * 16 + rr) * K + kbeg + cc;

    const int fslot = ((quad + (ml >> 1)) & 3) * 8;

#pragma unroll
    for (int p = 0; p < PK; p++) {
        load_lds16(Aa + p * 32, &As[p][wave * 512]);
        if (wave < CBCH) load_lds16(Bb + p * 32, &Bs[p][wave * 512]);
    }
    __syncthreads();

    const int steps = Kslice / (32 * PK);
    for (int s = 0; s < steps; s++) {
        const int cb = (s & 1) * PK, nb = cb ^ PK;
        const bool more = (s + 1 < steps);
        if (more) {
#pragma unroll
            for (int p = 0; p < PK; p++) {
                const int k0 = ((s + 1) * PK + p) * 32;
                load_lds16(Aa + k0, &As[nb + p][wave * 512]);
                if (wave < CBCH) load_lds16(Bb + k0, &Bs[nb + p][wave * 512]);
            }
        }

#pragma unroll
        for (int p = 0; p < PK; p++) {
            bf16x8 af[2], bfr[FN];
#pragma unroll
            for (int i = 0; i < 2; i++)
                af[i] = *(const bf16x8*)&As[cb + p][(wm + i * 16 + ml) * 32 + fslot];
#pragma unroll
            for (int j = 0; j < FN; j++)
                bfr[j] = *(const bf16x8*)&Bs[cb + p][(wn + j * 16 + ml) * 32 + fslot];

#pragma unroll
            for (int i = 0; i < 2; i++)
#pragma unroll
                for (int j = 0; j < FN; j++)
                    acc[i][j] = __builtin_amdgcn_mfma_f32_16x16x32_bf16(
                        af[i], bfr[j], acc[i][j], 0, 0, 0);
        }

        if (more) __syncthreads();
    }

    unsigned short* op = outp + (size_t)bzi * zstride;
#pragma unroll
    for (int i = 0; i < 2; i++)
#pragma unroll
        for (int j = 0; j < FN; j++)
#pragma unroll
            for (int r = 0; r < 4; r++) {
                const int row = bm + wm + i * 16 + quad * 4 + r;  // C/D row=quad*4+reg
                const int col = bn + wn + j * 16 + ml;            // C/D col=lane&15
                const float v = acc[i][j][r];
                if (EPI == 0) {
                    op[(size_t)row * N + col] = f2b(v);
                } else if (EPI == 2) {
                    const float u = v + bias[col];
                    const float g = 0.5f * u * (1.0f + fast_erf(u * 0.70710678118654752f));
                    outb[(size_t)row * N + col] = f2b(g);
                } else {
                    // split qkv: col -> (which, head, dim); head-major bf16
                    const int which = col >> 9;
                    const int hh = (col & 511) >> 6;
                    const int dim = col & 63;
                    unsigned short* dst =
                        which == 0 ? outq : (which == 1 ? outk : outv);
                    dst[((size_t)hh * MROWS + row) * HD + dim] = f2b(v);
                }
            }
}

// ---------------------------------------------------------------------------
// Split-K reduce (bf16 partials, Z slices) + residual + bias, optionally
// fused with the NEXT LayerNorm. One wave per row. In-place xout==xin safe.
// ---------------------------------------------------------------------------
template<bool DO_LN, int Z>
__global__ __launch_bounds__(256) void reduce_kernel(
    const float* __restrict__ xin,
    const unsigned short* __restrict__ part,   // [Z][MROWS x DM] bf16
    const float* __restrict__ bias,            // DM
    const float* __restrict__ lns, const float* __restrict__ lnb,
    float* __restrict__ xout, unsigned short* __restrict__ h)
{
    const int wid  = blockIdx.x * 4 + (threadIdx.x >> 6);
    const int lane = threadIdx.x & 63;
    const int c0 = lane * 4, c1 = 256 + lane * 4;
    const size_t ro = (size_t)wid * DM;

    float4 a0 = *(const float4*)&xin[ro + c0];
    float4 a1 = *(const float4*)&xin[ro + c1];
#pragma unroll
    for (int z = 0; z < Z; z++) {
        const unsigned short* p = part + (size_t)z * (MROWS * (size_t)DM) + ro;
        const ushort4 p0 = *(const ushort4*)&p[c0];
        const ushort4 p1 = *(const ushort4*)&p[c1];
        a0.x += b2f(p0.x); a0.y += b2f(p0.y); a0.z += b2f(p0.z); a0.w += b2f(p0.w);
        a1.x += b2f(p1.x); a1.y += b2f(p1.y); a1.z += b2f(p1.z); a1.w += b2f(p1.w);
    }
    a0.x += bias[c0+0]; a0.y += bias[c0+1]; a0.z += bias[c0+2]; a0.w += bias[c0+3];
    a1.x += bias[c1+0]; a1.y += bias[c1+1]; a1.z += bias[c1+2]; a1.w += bias[c1+3];

    *(float4*)&xout[ro + c0] = a0;
    *(float4*)&xout[ro + c1] = a1;

    if (DO_LN) {
        float s = a0.x + a0.y + a0.z + a0.w + a1.x + a1.y + a1.z + a1.w;
        float q = a0.x*a0.x + a0.y*a0.y + a0.z*a0.z + a0.w*a0.w
                + a1.x*a1.x + a1.y*a1.y + a1.z*a1.z + a1.w*a1.w;
#pragma unroll
        for (int off = 32; off; off >>= 1) {
            s += __shfl_xor(s, off, 64);
            q += __shfl_xor(q, off, 64);
        }
        const float mean = s * (1.0f / DM);
        const float var  = q * (1.0f / DM) - mean * mean;
        const float rs   = rsqrtf(var + 1e-5f);
        unsigned short* hr = h + ro;
        ushort4 o0, o1;
        o0.x = f2b((a0.x - mean) * rs * lns[c0+0] + lnb[c0+0]);
        o0.y = f2b((a0.y - mean) * rs * lns[c0+1] + lnb[c0+1]);
        o0.z = f2b((a0.z - mean) * rs * lns[c0+2] + lnb[c0+2]);
        o0.w = f2b((a0.w - mean) * rs * lns[c0+3] + lnb[c0+3]);
        o1.x = f2b((a1.x - mean) * rs * lns[c1+0] + lnb[c1+0]);
        o1.y = f2b((a1.y - mean) * rs * lns[c1+1] + lnb[c1+1]);
        o1.z = f2b((a1.z - mean) * rs * lns[c1+2] + lnb[c1+2]);
        o1.w = f2b((a1.w - mean) * rs * lns[c1+3] + lnb[c1+3]);
        *(ushort4*)&hr[c0] = o0;
        *(ushort4*)&hr[c1] = o1;
    }
}

// ---------------------------------------------------------------------------
extern "C" void kernel_launch(void* const* d_in, const int* in_sizes, int n_in,
                              void* d_out, int out_size, void* d_ws, size_t ws_size,
                              hipStream_t stream)
{
    (void)in_sizes; (void)n_in; (void)out_size; (void)ws_size;
    const float* x_in   = (const float*)d_in[0];
    const float* ln1_s  = (const float*)d_in[1];
    const float* ln1_b  = (const float*)d_in[2];
    const float* qkv_w  = (const float*)d_in[3];
    const float* proj_w = (const float*)d_in[4];
    const float* proj_b = (const float*)d_in[5];
    const float* ln2_s  = (const float*)d_in[6];
    const float* ln2_b  = (const float*)d_in[7];
    const float* w1     = (const float*)d_in[8];
    const float* b1     = (const float*)d_in[9];
    const float* w2     = (const float*)d_in[10];
    const float* b2     = (const float*)d_in[11];

    // Workspace carve-up (bytes)
    char* ws = (char*)d_ws;
    float*          xbuf = (float*)(ws);                        //   0 MB, 8 MB
    unsigned short* qhb  = (unsigned short*)(ws + 8388608);     //   8 MB, 4 MB bf16 [8][4096][64]
    unsigned short* khb  = (unsigned short*)(ws + 12582912);    //  12 MB, 4 MB
    unsigned short* vhb  = (unsigned short*)(ws + 16777216);    //  16 MB, 4 MB
    unsigned short* ubuf = (unsigned short*)(ws + 33554432);    //  32 MB, 16 MB bf16
    unsigned short* hbuf = (unsigned short*)(ws + 50331648);    //  48 MB, 4 MB
    unsigned short* obuf = (unsigned short*)(ws + 54525952);    //  52 MB, 4 MB
    unsigned short* part = (unsigned short*)(ws + 58720256);    //  56 MB, 16 MB bf16 [4][4096x512]
    unsigned short* qkvT = (unsigned short*)(ws + 92274688);    //  88 MB
    unsigned short* projT= (unsigned short*)(ws + 96993280);
    unsigned short* w1T  = (unsigned short*)(ws + 98566144);
    unsigned short* w2T  = (unsigned short*)(ws + 104857600);   // ends 106 MB

    const size_t ZS = (size_t)MROWS * DM;   // partial-slice stride (elements)

    // All weight transposes + depth-0 LN1 in ONE launch (9216 + 1024 blocks).
    prep_kernel<<<10240, 256, 0, stream>>>(
        qkv_w, proj_w, w1, w2, qkvT, projT, w1T, w2T,
        x_in, ln1_s, ln1_b, hbuf);

    for (int d = 0; d < NDEPTH; d++) {
        const int dil = 1 << d;
        const float* xin = (d == 0) ? x_in : xbuf;   // x residual source

        // qkv = h @ qkv_w -> head-major q/k/v. 8-wave TN=64: 768 blocks = 3/CU.
        gemm8_kernel<3, 64><<<768, 512, 0, stream>>>(
            hbuf, qkvT + (size_t)d * 1536 * 512, nullptr, nullptr, nullptr,
            qhb, khb, vhb, 1536, 512, 512, 0, 24, 32);
        // dilated attention -> o (bf16). 32-query tiles: 1024 blocks = 4/CU.
        attn_kernel<<<2 * NH * (TSEQ / 32), 256, 0, stream>>>(qhb, khb, vhb, obuf, dil);
        // proj partials: split-K x2, Kslice 256. 8-wave TN=64: 512 blocks (8,32,2).
        gemm8_kernel<0, 64><<<512, 512, 0, stream>>>(
            obuf, projT + (size_t)d * 512 * 512, nullptr, part, nullptr,
            nullptr, nullptr, nullptr, 512, 512, 256, ZS, 8, 32);
        // x = xin + sum(part) + proj_b ; h = LN2(x) fused
        reduce_kernel<true, 2><<<MROWS / 4, 256, 0, stream>>>(
            xin, part, proj_b + d * DM, ln2_s + d * DM, ln2_b + d * DM,
            xbuf, hbuf);
        // u = gelu(h @ w1 + b1). 8-wave TN=128: 512 blocks (16,32).
        gemm8_kernel<2, 128><<<512, 512, 0, stream>>>(
            hbuf, w1T + (size_t)d * 2048 * 512, b1 + d * 2048, nullptr, ubuf,
            nullptr, nullptr, nullptr, 2048, 512, 512, 0, 16, 32);
        // w2 partials: split-K x4, Kslice 512. 8-wave TN=128: 512 blocks (4,32,4).
        gemm8_kernel<0, 128><<<512, 512, 0, stream>>>(
            ubuf, w2T + (size_t)d * 512 * 2048, nullptr, part, nullptr,
            nullptr, nullptr, nullptr, 512, 2048, 512, ZS, 4, 32);
        // x += sum(part) + b2 ; fuse next depth's LN1 (or final write to d_out)
        if (d < NDEPTH - 1) {
            reduce_kernel<true, 4><<<MROWS / 4, 256, 0, stream>>>(
                xbuf, part, b2 + d * DM, ln1_s + (d+1) * DM, ln1_b + (d+1) * DM,
                xbuf, hbuf);
        } else {
            reduce_kernel<false, 4><<<MROWS / 4, 256, 0, stream>>>(
                xbuf, part, b2 + d * DM, nullptr, nullptr,
                (float*)d_out, nullptr);
        }
    }
}